// Round 1
// baseline (365.386 us; speedup 1.0000x reference)
//
#include <hip/hip_runtime.h>

// out[1,8192] = x[1,8192] @ W[8192,8192] + b[8192]   (all fp32)
// Memory-bound: stream W (256 MiB) once, coalesced float4 column loads.

#define IN_LEN   8192
#define OUT_LEN  8192
#define K_CHUNK  128              // rows per block (K split for parallelism)
#define THREADS  256

__global__ __launch_bounds__(256)
void init_out_kernel(const float* __restrict__ b, float* __restrict__ out) {
    int j = blockIdx.x * blockDim.x + threadIdx.x;
    if (j < OUT_LEN) out[j] = b[j];
}

__global__ __launch_bounds__(256)
void matvec_partial_kernel(const float* __restrict__ x,
                           const float* __restrict__ W,
                           float* __restrict__ out) {
    // Each thread owns 4 consecutive output columns (one float4).
    const int col4  = blockIdx.x * THREADS + threadIdx.x;   // float4 column index
    const int kbase = blockIdx.y * K_CHUNK;

    const float4* __restrict__ W4 = (const float4*)W;
    float4 acc = make_float4(0.f, 0.f, 0.f, 0.f);

#pragma unroll 8
    for (int i = 0; i < K_CHUNK; ++i) {
        const float xs = x[kbase + i];                       // block-uniform -> s_load
        const float4 w = W4[(kbase + i) * (OUT_LEN / 4) + col4];
        acc.x += xs * w.x;
        acc.y += xs * w.y;
        acc.z += xs * w.z;
        acc.w += xs * w.w;
    }

    float* o = out + col4 * 4;
    atomicAdd(o + 0, acc.x);
    atomicAdd(o + 1, acc.y);
    atomicAdd(o + 2, acc.z);
    atomicAdd(o + 3, acc.w);
}

extern "C" void kernel_launch(void* const* d_in, const int* in_sizes, int n_in,
                              void* d_out, int out_size, void* d_ws, size_t ws_size,
                              hipStream_t stream) {
    const float* x = (const float*)d_in[0];   // (1, 8192)
    const float* W = (const float*)d_in[1];   // (8192, 8192) row-major
    const float* b = (const float*)d_in[2];   // (8192,)
    float* out = (float*)d_out;               // (1, 8192)

    // 1) out = b  (d_out is re-poisoned to 0xAA before every launch)
    init_out_kernel<<<dim3(OUT_LEN / THREADS), dim3(THREADS), 0, stream>>>(b, out);

    // 2) out += partial dot products, split over (column-chunks, K-chunks)
    dim3 grid(OUT_LEN / (4 * THREADS), IN_LEN / K_CHUNK);   // (8, 64) = 512 blocks
    matvec_partial_kernel<<<grid, dim3(THREADS), 0, stream>>>(x, W, out);
}